// Round 2
// 1753.182 us; speedup vs baseline: 1.2465x; 1.2465x over previous
//
#include <hip/hip_runtime.h>

// QuantizedLinear: out[M=8192, N=16384] = (x[M,K=4096] @ (w_int[N,K]*scale[N]).T) + bias[N]
// Strategy: convert x (fp32->bf16 RTNE) and w (int32->bf16, exact for |w|<=127) into
// workspace, then bf16 MFMA GEMM. 256x256 tile, 8 waves, BK=32, 4 rotating LDS buffers
// (128KB), counted vmcnt(8) pipeline (never drains to 0 in the main loop), raw s_barrier
// phases with setprio(1) around 16-MFMA clusters, XCD swizzle.
//
// Pipeline ledger (tile t in buf t&3):
//   (t,P1): ds_read A[0..3]+B[0..3] of tile t; issue STAGE_A(t+3); bar; lgkm0; 16 MFMA; bar
//   (t,P2): ds_read A[4..7];            issue STAGE_B(t+3); vmcnt(8); bar; lgkm0; 16 MFMA; bar
//   - overwrite safety: tile t's last reads drain at (t,P2) lgkm0, before (t,P2) end bar;
//     buf t&3 is next written by STAGE_A(t+4) issued at (t+1,P1), after that barrier.
//   - read safety: tile t staged at (t-3,P1/P2); each wave's vmcnt(8) at (t-1,P2) leaves
//     only tiles t+1,t+2 (8 loads) outstanding -> its portion of tile t complete; the
//     following barrier ensures ALL waves executed their vmcnt(8) -> whole tile visible.
//   Prologue: stage tiles 0,1,2 (12 loads), vmcnt(8) -> tile0 done. Tail peels 125..127.
// No deadlock is possible: uniform control flow (same barrier count in every wave),
// and all waitcnts retire unconditionally.

typedef __bf16 bf16x8 __attribute__((ext_vector_type(8)));
typedef float floatx4 __attribute__((ext_vector_type(4)));
typedef unsigned short ushort_t;

#define GEMM_M 8192
#define GEMM_N 16384
#define GEMM_K 4096
#define BK 32
#define NTILES (GEMM_K / BK)  // 128

__device__ inline unsigned int f2bf(float f) {
    unsigned int u = __float_as_uint(f);
    unsigned int r = u + 0x7FFFu + ((u >> 16) & 1u);
    return r >> 16;
}

// ---- conversion kernels: 8 elems / thread, 16B stores (unchanged, ~BW-bound) ----
__global__ __launch_bounds__(256) void cvt_f32_bf16(const float4* __restrict__ in,
                                                    uint4* __restrict__ outp) {
    int i = blockIdx.x * 256 + threadIdx.x;
    float4 a = in[2 * i];
    float4 b = in[2 * i + 1];
    uint4 o;
    o.x = f2bf(a.x) | (f2bf(a.y) << 16);
    o.y = f2bf(a.z) | (f2bf(a.w) << 16);
    o.z = f2bf(b.x) | (f2bf(b.y) << 16);
    o.w = f2bf(b.z) | (f2bf(b.w) << 16);
    outp[i] = o;
}

__global__ __launch_bounds__(256) void cvt_i32_bf16(const int4* __restrict__ in,
                                                    uint4* __restrict__ outp) {
    int i = blockIdx.x * 256 + threadIdx.x;
    int4 a = in[2 * i];
    int4 b = in[2 * i + 1];
    uint4 o;
    o.x = f2bf((float)a.x) | (f2bf((float)a.y) << 16);
    o.y = f2bf((float)a.z) | (f2bf((float)a.w) << 16);
    o.z = f2bf((float)b.x) | (f2bf((float)b.y) << 16);
    o.w = f2bf((float)b.z) | (f2bf((float)b.w) << 16);
    outp[i] = o;
}

// ---- GEMM ----
#define GLOAD_LDS16(gsrc, ldst)                                                        \
    __builtin_amdgcn_global_load_lds(                                                  \
        (const __attribute__((address_space(1))) void*)(gsrc),                         \
        (__attribute__((address_space(3))) void*)(ldst), 16, 0, 0)

// Stage one 16KB unit (256 rows x 32 K-elems) of tile tt. Dest is linear LDS
// (global_load_lds requirement, m104); the swizzle is pre-applied to the GLOBAL
// source address (qp below), inverse of the read-side swizzle (rule #21).
#define STAGE_A(tt)                                                                    \
    do {                                                                               \
        const int bo_s = ((tt) & 3) * 16384;                                           \
        GLOAD_LDS16(srcA + (size_t)(tt) * BK, &lds[bo_s + dstA]);                      \
        GLOAD_LDS16(srcA + (size_t)(tt) * BK + (size_t)16 * GEMM_K,                    \
                    &lds[bo_s + dstA + 512]);                                          \
    } while (0)

#define STAGE_B(tt)                                                                    \
    do {                                                                               \
        const int bo_s = ((tt) & 3) * 16384;                                           \
        GLOAD_LDS16(srcB + (size_t)(tt) * BK, &lds[bo_s + dstB]);                      \
        GLOAD_LDS16(srcB + (size_t)(tt) * BK + (size_t)16 * GEMM_K,                    \
                    &lds[bo_s + dstB + 512]);                                          \
    } while (0)

#define VM8 asm volatile("s_waitcnt vmcnt(8)" ::: "memory")
#define VM4 asm volatile("s_waitcnt vmcnt(4)" ::: "memory")
#define VM0 asm volatile("s_waitcnt vmcnt(0)" ::: "memory")
#define VMNONE ((void)0)

#define MFMA16(ACCBASE)                                                                \
    _Pragma("unroll") for (int i_ = 0; i_ < 4; ++i_)                                   \
        _Pragma("unroll") for (int j_ = 0; j_ < 4; ++j_)                               \
            acc[(ACCBASE) + i_][j_] = __builtin_amdgcn_mfma_f32_16x16x32_bf16(         \
                af[i_], bfr[j_], acc[(ACCBASE) + i_][j_], 0, 0, 0);

// One K-tile = 2 phases. BO = (t&3)*16384 (compile-time at each expansion site).
// sched_barrier(0) on BOTH sides of every s_barrier: no memory op (ds_read or
// global_load_lds issue) may be moved across a barrier by the scheduler.
#define KTILE(BO, SA, SB, VMW)                                                         \
    {                                                                                  \
        bf16x8 af[4], bfr[4];                                                          \
        _Pragma("unroll") for (int i_ = 0; i_ < 4; ++i_)                               \
            af[i_] = *(const bf16x8*)&lds[(BO) + aoff + i_ * 512];                     \
        _Pragma("unroll") for (int j_ = 0; j_ < 4; ++j_)                               \
            bfr[j_] = *(const bf16x8*)&lds[(BO) + boff + j_ * 512];                    \
        SA;                                                                            \
        __builtin_amdgcn_sched_barrier(0);                                             \
        __builtin_amdgcn_s_barrier();                                                  \
        asm volatile("s_waitcnt lgkmcnt(0)" ::: "memory");                             \
        __builtin_amdgcn_sched_barrier(0);                                             \
        __builtin_amdgcn_s_setprio(1);                                                 \
        MFMA16(0)                                                                      \
        __builtin_amdgcn_s_setprio(0);                                                 \
        __builtin_amdgcn_sched_barrier(0);                                             \
        __builtin_amdgcn_s_barrier();                                                  \
        __builtin_amdgcn_sched_barrier(0);                                             \
        _Pragma("unroll") for (int i_ = 0; i_ < 4; ++i_)                               \
            af[i_] = *(const bf16x8*)&lds[(BO) + aoff + 2048 + i_ * 512];              \
        SB;                                                                            \
        VMW;                                                                           \
        __builtin_amdgcn_sched_barrier(0);                                             \
        __builtin_amdgcn_s_barrier();                                                  \
        asm volatile("s_waitcnt lgkmcnt(0)" ::: "memory");                             \
        __builtin_amdgcn_sched_barrier(0);                                             \
        __builtin_amdgcn_s_setprio(1);                                                 \
        MFMA16(4)                                                                      \
        __builtin_amdgcn_s_setprio(0);                                                 \
        __builtin_amdgcn_sched_barrier(0);                                             \
        __builtin_amdgcn_s_barrier();                                                  \
        __builtin_amdgcn_sched_barrier(0);                                             \
    }

__global__ __launch_bounds__(512, 2) void gemm_bf16(const ushort_t* __restrict__ xb,
                                                    const ushort_t* __restrict__ wb,
                                                    const float* __restrict__ scale,
                                                    const float* __restrict__ bias,
                                                    float* __restrict__ out) {
    // 4 rotating buffers x (A 16KB + B 16KB) = 128 KB
    __shared__ __align__(16) ushort_t lds[65536];

    const int tid  = threadIdx.x;
    const int wave = tid >> 6;   // 0..7
    const int lane = tid & 63;
    const int l16  = lane & 15;
    const int q    = lane >> 4;  // K-quarter of the 32-wide slice
    const int wm   = wave >> 2;  // 0..1  (wave tile: 128 rows x 64 cols)
    const int wn   = wave & 3;   // 0..3

    // XCD-aware swizzle: 2048 blocks, nwg%8==0 -> simple form is bijective
    const int lin = blockIdx.y * gridDim.x + blockIdx.x;
    const int swz = (lin & 7) * (2048 / 8) + (lin >> 3);
    const int bx  = swz & 63;  // N-tile
    const int by  = swz >> 6;  // M-tile
    const size_t rowBase = (size_t)by * 256;
    const size_t colBase = (size_t)bx * 256;

    // --- staging source (per-lane; swizzle pre-applied to global addr) ---
    // phys slot s at row r holds logical granule q = s ^ ((r>>1)&3); per-lane this
    // reduces to qp = (lane&3) ^ ((lane>>3)&3) (row bases are multiples of 16).
    const int srow = lane >> 2;  // 0..15
    const int qp   = (lane & 3) ^ ((lane >> 3) & 3);
    const ushort_t* srcA = xb + (rowBase + (size_t)(wave * 32 + srow)) * GEMM_K + qp * 8;
    const ushort_t* srcB = wb + (colBase + (size_t)(wave * 32 + srow)) * GEMM_K + qp * 8;
    const int dstA = wave * 1024;         // ushort offset, +512 for 2nd 16-row group
    const int dstB = 8192 + wave * 1024;  // B at +16KB within buffer

    // --- read-side fragment offsets (ushorts); row r slot = q ^ ((r>>1)&3) ---
    const int swzrd = (q ^ ((l16 >> 1) & 3)) << 3;
    const int aoff  = (wm * 128 + l16) * 32 + swzrd;         // + i*512 per M-frag
    const int boff  = 8192 + (wn * 64 + l16) * 32 + swzrd;   // + j*512 per N-frag

    floatx4 acc[8][4] = {};

    // --- prologue: stage tiles 0,1,2 (12 loads); tile0 complete after vmcnt(8) ---
    STAGE_A(0); STAGE_B(0);
    STAGE_A(1); STAGE_B(1);
    STAGE_A(2); STAGE_B(2);
    VM8;
    __builtin_amdgcn_sched_barrier(0);
    __builtin_amdgcn_s_barrier();
    __builtin_amdgcn_sched_barrier(0);

    // --- main loop: t = 0..123 (stages tiles 3..126), then peeled tail ---
#pragma unroll 1
    for (int o = 0; o < 31; ++o) {
        const int t = o * 4;
        KTILE(0,     STAGE_A(t + 3), STAGE_B(t + 3), VM8);
        KTILE(16384, STAGE_A(t + 4), STAGE_B(t + 4), VM8);
        KTILE(32768, STAGE_A(t + 5), STAGE_B(t + 5), VM8);
        KTILE(49152, STAGE_A(t + 6), STAGE_B(t + 6), VM8);
    }
    KTILE(0,     STAGE_A(127), STAGE_B(127), VM8);   // t=124
    KTILE(16384, VMNONE, VMNONE, VM4);               // t=125: only tile127 (4) in flight
    KTILE(32768, VMNONE, VMNONE, VM0);               // t=126: drain tile127
    KTILE(49152, VMNONE, VMNONE, VMNONE);            // t=127

    // --- epilogue: C/D layout col=lane&15, row=(lane>>4)*4+reg (m89/m91 verified) ---
    float scl[4], bs[4];
#pragma unroll
    for (int j = 0; j < 4; ++j) {
        const size_t col = colBase + wn * 64 + j * 16 + l16;
        scl[j] = scale[col];
        bs[j]  = bias[col];
    }
#pragma unroll
    for (int i = 0; i < 8; ++i) {
        const size_t row0 = rowBase + wm * 128 + i * 16 + q * 4;
#pragma unroll
        for (int r = 0; r < 4; ++r) {
            float* orow = out + (row0 + r) * (size_t)GEMM_N;
#pragma unroll
            for (int j = 0; j < 4; ++j) {
                const size_t col = colBase + wn * 64 + j * 16 + l16;
                orow[col] = acc[i][j][r] * scl[j] + bs[j];
            }
        }
    }
}

extern "C" void kernel_launch(void* const* d_in, const int* in_sizes, int n_in,
                              void* d_out, int out_size, void* d_ws, size_t ws_size,
                              hipStream_t stream) {
    const float* x     = (const float*)d_in[0];   // (4,2048,4096) fp32
    const int*   w     = (const int*)d_in[1];     // (16384,4096) int32 in [-127,127]
    const float* scale = (const float*)d_in[2];   // (16384,1) fp32
    const float* bias  = (const float*)d_in[3];   // (16384,) fp32
    float*       out   = (float*)d_out;           // (4,2048,16384) fp32

    ushort_t* xb = (ushort_t*)d_ws;                                // 64 MB
    ushort_t* wb = (ushort_t*)d_ws + (size_t)GEMM_M * GEMM_K;      // 128 MB

    cvt_f32_bf16<<<(GEMM_M * (size_t)GEMM_K) / 8 / 256, 256, 0, stream>>>(
        (const float4*)x, (uint4*)xb);
    cvt_i32_bf16<<<((size_t)GEMM_N * GEMM_K) / 8 / 256, 256, 0, stream>>>(
        (const int4*)w, (uint4*)wb);

    dim3 grid(GEMM_N / 256, GEMM_M / 256);  // (64, 32) = 2048 blocks
    gemm_bf16<<<grid, dim3(512), 0, stream>>>(xb, wb, scale, bias, out);
}